// Round 13
// baseline (376.227 us; speedup 1.0000x reference)
//
#include <hip/hip_runtime.h>
#include <hip/hip_bf16.h>

typedef __attribute__((ext_vector_type(8))) __bf16 bf16x8;
typedef __attribute__((ext_vector_type(4))) __bf16 bf16x4;
typedef __attribute__((ext_vector_type(4))) float  f32x4;

__device__ __forceinline__ void gload_lds16(const __bf16* g, __bf16* l) {
    __builtin_amdgcn_global_load_lds(
        (const __attribute__((address_space(1))) void*)g,
        (__attribute__((address_space(3))) void*)l, 16, 0, 0);
}

// Soft barrier: ds-write visibility (lgkmcnt(0)) + rendezvous, but does NOT
// drain vmcnt -> register prefetch loads stay in flight across the barrier.
#define SOFT_BARRIER()                                            \
    do {                                                          \
        asm volatile("s_waitcnt lgkmcnt(0)" ::: "memory");        \
        __builtin_amdgcn_s_barrier();                             \
        asm volatile("" ::: "memory");                            \
    } while (0)

// ---------------------------------------------------------------------------
// All weight transposes (fp32 [K][N] -> bf16 [N][K]) + bias concat, ONE launch.
// ---------------------------------------------------------------------------
__global__ __launch_bounds__(256) void transpose_all(
    const float* __restrict__ wq, const float* __restrict__ wk,
    const float* __restrict__ wv, const float* __restrict__ wo,
    const float* __restrict__ w1, const float* __restrict__ w2,
    __bf16* __restrict__ wqkvT, __bf16* __restrict__ woT,
    __bf16* __restrict__ w1T, __bf16* __restrict__ w2T,
    const float* __restrict__ bq, const float* __restrict__ bk,
    const float* __restrict__ bv, float* __restrict__ bqkv) {
    __shared__ float t[32][33];
    const int bid = blockIdx.x;
    if (bid >= 12288) {   // bias concat tail
        const int i = (bid - 12288) * 256 + threadIdx.x;
        bqkv[i] = bq[i]; bqkv[1024 + i] = bk[i]; bqkv[2048 + i] = bv[i];
        return;
    }
    const float* in; __bf16* out; int K, N, nb, kb;
    if (bid < 4096) {
        const int which = bid >> 10, tt = bid & 1023;
        K = 1024; N = 1024;
        in  = which == 0 ? wq : which == 1 ? wk : which == 2 ? wv : wo;
        out = which == 3 ? woT : wqkvT + (size_t)which * 1048576;
        nb = (tt & 31) * 32; kb = (tt >> 5) * 32;
    } else if (bid < 8192) {
        const int tt = bid - 4096;
        in = w1; out = w1T; K = 1024; N = 4096;
        nb = (tt & 127) * 32; kb = (tt >> 7) * 32;
    } else {
        const int tt = bid - 8192;
        in = w2; out = w2T; K = 4096; N = 1024;
        nb = (tt & 31) * 32; kb = (tt >> 5) * 32;
    }
    const int tx = threadIdx.x & 31, ty = threadIdx.x >> 5;
#pragma unroll
    for (int i = 0; i < 32; i += 8)
        t[ty + i][tx] = in[(size_t)(kb + ty + i) * N + nb + tx];
    __syncthreads();
#pragma unroll
    for (int i = 0; i < 32; i += 8)
        out[(size_t)(nb + ty + i) * K + kb + tx] = (__bf16)t[tx][ty + i];
}

// ---------------------------------------------------------------------------
// LayerNorm over D=1024, one block per row, fp32 in -> bf16 out
// ---------------------------------------------------------------------------
__global__ __launch_bounds__(256) void ln_to_bf16(const float* __restrict__ x,
                                                  const float* __restrict__ g,
                                                  const float* __restrict__ bb,
                                                  __bf16* __restrict__ out) {
    const int row = blockIdx.x, t = threadIdx.x;
    const float4 v = ((const float4*)(x + (size_t)row * 1024))[t];
    float s  = v.x + v.y + v.z + v.w;
    float ss = v.x * v.x + v.y * v.y + v.z * v.z + v.w * v.w;
#pragma unroll
    for (int off = 32; off; off >>= 1) {
        s  += __shfl_down(s, off);
        ss += __shfl_down(ss, off);
    }
    __shared__ float ps[4], pss[4];
    if ((t & 63) == 0) { ps[t >> 6] = s; pss[t >> 6] = ss; }
    __syncthreads();
    s  = ps[0] + ps[1] + ps[2] + ps[3];
    ss = pss[0] + pss[1] + pss[2] + pss[3];
    const float mu   = s * (1.0f / 1024.0f);
    const float var  = ss * (1.0f / 1024.0f) - mu * mu;
    const float rinv = rsqrtf(var + 1e-5f);
    const float4 gv = ((const float4*)g)[t];
    const float4 bv = ((const float4*)bb)[t];
    bf16x4 o;
    o[0] = (__bf16)((v.x - mu) * rinv * gv.x + bv.x);
    o[1] = (__bf16)((v.y - mu) * rinv * gv.y + bv.y);
    o[2] = (__bf16)((v.z - mu) * rinv * gv.z + bv.z);
    o[3] = (__bf16)((v.w - mu) * rinv * gv.w + bv.w);
    *(bf16x4*)(out + (size_t)row * 1024 + 4 * t) = o;
}

// ---------------------------------------------------------------------------
// 256x256 8-phase GEMM (FFN1). 2D per-XCD chunk. MODE 1: relu bf16 out.
// ---------------------------------------------------------------------------
template <int MODE>
__global__ __launch_bounds__(512, 2) void gemm256(const __bf16* __restrict__ A,
                                                  const __bf16* __restrict__ BT,
                                                  const float* __restrict__ bias,
                                                  __bf16* __restrict__ outp,
                                                  int M, int N, int K, int NMB) {
    __shared__ __align__(16) __bf16 lds[65536];
    const int bid = blockIdx.x;
    const int c8 = bid & 7, loc = bid >> 3;       // XCD id, chunk-local index
    const int MH = NMB >> 3;                      // bm rows per XCD chunk
    const int bm = (c8 * MH + loc % MH) * 256;
    const int bn = (loc / MH) * 256;
    const int tid = threadIdx.x, l = tid & 63, w = tid >> 6;
    const int wm = (w >> 2) * 128, wn = (w & 3) * 64;
    const int lg = l >> 4, lm = l & 15;
    const int NT = K >> 6;

    const __bf16* gsrc[4];
    int ldst[4];
#pragma unroll
    for (int j = 0; j < 4; ++j) {
        const unsigned X = (unsigned)(((j & 1) << 13) + (w << 10) + l * 16);
        const unsigned L = X ^ (((X >> 7) & 7u) << 4);
        const int row = L >> 6, col = (L & 63) >> 1;
        gsrc[j] = (j < 2 ? A + (size_t)(bm + row) * K : BT + (size_t)(bn + row) * K) + col;
        ldst[j] = ((j < 2 ? 0 : 16384) + ((j & 1) << 13) + (w << 10)) >> 1;
    }
    int aoff[2][4], boff[4];
#pragma unroll
    for (int mh = 0; mh < 2; ++mh)
#pragma unroll
        for (int fr = 0; fr < 4; ++fr) {
            const unsigned Lb = (unsigned)(wm + mh * 64 + fr * 16 + lm) * 64 + lg * 16;
            aoff[mh][fr] = (int)(Lb ^ (((Lb >> 7) & 7u) << 4)) >> 1;
        }
#pragma unroll
    for (int n = 0; n < 4; ++n) {
        const unsigned Lb = (unsigned)(wn + n * 16 + lm) * 64 + lg * 16;
        boff[n] = (int)(16384u + (Lb ^ (((Lb >> 7) & 7u) << 4))) >> 1;
    }

    f32x4 acc[8][4];
#pragma unroll
    for (int m = 0; m < 8; ++m)
#pragma unroll
        for (int n = 0; n < 4; ++n) acc[m][n] = f32x4{0.f, 0.f, 0.f, 0.f};

#define ISSUE_SUB(u)                                                          \
    do {                                                                      \
        __bf16* sbp = lds + (((u) & 3) << 14);                                \
        const int go = (u) << 5;                                              \
        _Pragma("unroll")                                                     \
        for (int j = 0; j < 4; ++j) gload_lds16(gsrc[j] + go, sbp + ldst[j]); \
    } while (0)

#define MFMA16(MH_, BREG)                                                     \
    do {                                                                      \
        __builtin_amdgcn_s_setprio(1);                                        \
        _Pragma("unroll")                                                     \
        for (int i = 0; i < 4; ++i)                                           \
            _Pragma("unroll")                                                 \
            for (int n = 0; n < 4; ++n)                                       \
                acc[(MH_)*4 + i][n] = __builtin_amdgcn_mfma_f32_16x16x32_bf16(\
                    af[i], BREG[n], acc[(MH_)*4 + i][n], 0, 0, 0);            \
        __builtin_amdgcn_s_setprio(0);                                        \
    } while (0)

    ISSUE_SUB(0); ISSUE_SUB(1); ISSUE_SUB(2); ISSUE_SUB(3);
    asm volatile("s_waitcnt vmcnt(8)" ::: "memory");
    __builtin_amdgcn_s_barrier();

    for (int t = 0; t < NT; ++t) {
        const int sa = ((2 * t) & 3) << 14, sb = ((2 * t + 1) & 3) << 14;
        bf16x8 af[4], b0[4], b1[4];
#pragma unroll
        for (int fr = 0; fr < 4; ++fr) af[fr] = *(const bf16x8*)(lds + sa + aoff[0][fr]);
#pragma unroll
        for (int n = 0; n < 4; ++n) b0[n] = *(const bf16x8*)(lds + sa + boff[n]);
        asm volatile("" ::: "memory");
        __builtin_amdgcn_s_barrier();
        __builtin_amdgcn_sched_barrier(0);
        MFMA16(0, b0);
        __builtin_amdgcn_sched_barrier(0);
        __builtin_amdgcn_s_barrier();
#pragma unroll
        for (int fr = 0; fr < 4; ++fr) af[fr] = *(const bf16x8*)(lds + sa + aoff[1][fr]);
        asm volatile("" ::: "memory");
        __builtin_amdgcn_s_barrier();
        __builtin_amdgcn_sched_barrier(0);
        MFMA16(1, b0);
        __builtin_amdgcn_sched_barrier(0);
        __builtin_amdgcn_s_barrier();
        if (t < NT - 2) ISSUE_SUB(2 * t + 4);
#pragma unroll
        for (int fr = 0; fr < 4; ++fr) af[fr] = *(const bf16x8*)(lds + sb + aoff[0][fr]);
#pragma unroll
        for (int n = 0; n < 4; ++n) b1[n] = *(const bf16x8*)(lds + sb + boff[n]);
        asm volatile("" ::: "memory");
        __builtin_amdgcn_s_barrier();
        __builtin_amdgcn_sched_barrier(0);
        MFMA16(0, b1);
        __builtin_amdgcn_sched_barrier(0);
        __builtin_amdgcn_s_barrier();
#pragma unroll
        for (int fr = 0; fr < 4; ++fr) af[fr] = *(const bf16x8*)(lds + sb + aoff[1][fr]);
        asm volatile("" ::: "memory");
        __builtin_amdgcn_s_barrier();
        __builtin_amdgcn_sched_barrier(0);
        MFMA16(1, b1);
        __builtin_amdgcn_sched_barrier(0);
        __builtin_amdgcn_s_barrier();
        if (t < NT - 2) {
            ISSUE_SUB(2 * t + 5);
            asm volatile("s_waitcnt vmcnt(8)" ::: "memory");
        } else if (t == NT - 2) {
            asm volatile("s_waitcnt vmcnt(0)" ::: "memory");
        }
        __builtin_amdgcn_s_barrier();
    }
#undef ISSUE_SUB
#undef MFMA16

#pragma unroll
    for (int m = 0; m < 8; ++m) {
        const int row = bm + wm + (m >> 2) * 64 + (m & 3) * 16 + lg * 4;
#pragma unroll
        for (int n = 0; n < 4; ++n) {
            const int col = bn + wn + n * 16 + lm;
            const float bvv = bias[col];
#pragma unroll
            for (int r = 0; r < 4; ++r) {
                const float v = acc[m][n][r] + bvv;
                outp[(size_t)(row + r) * N + col] =
                    (MODE == 1) ? (__bf16)fmaxf(v, 0.f) : (__bf16)v;
            }
        }
    }
}

// ---------------------------------------------------------------------------
// 128x128 GEMM, f32 out + residual (proj / FFN2, N=1024). MERGED PHASES.
// ---------------------------------------------------------------------------
__global__ __launch_bounds__(512, 4) void gemm128x128(const __bf16* __restrict__ A,
                                                      const __bf16* __restrict__ BT,
                                                      const float* __restrict__ bias,
                                                      const float* __restrict__ resid,
                                                      float* __restrict__ outp,
                                                      int M, int N, int K, int NMB) {
    __shared__ __align__(16) __bf16 lds[32768];   // 4 sub-buffers x 8192 elems
    const int bid = blockIdx.x;
    const int c8 = bid & 7, loc = bid >> 3;
    const int MH = NMB >> 3;
    const int bm = (c8 * MH + loc % MH) * 128;
    const int bn = (loc / MH) * 128;
    const int tid = threadIdx.x, l = tid & 63, w = tid >> 6;
    const int wm = (w >> 1) * 32, wn = (w & 1) * 64;
    const int lg = l >> 4, lm = l & 15;
    const int NT = K >> 6;

    const __bf16* gsrc[2];
    int ldst[2];
#pragma unroll
    for (int j = 0; j < 2; ++j) {
        const unsigned X = (unsigned)(tid * 16);
        const unsigned L = X ^ (((X >> 7) & 7u) << 4);
        const int row = L >> 6, col = (L & 63) >> 1;
        gsrc[j] = (j == 0 ? A + (size_t)(bm + row) * K : BT + (size_t)(bn + row) * K) + col;
        ldst[j] = ((j == 0 ? 0 : 8192) + (w << 10)) >> 1;
    }
    int aoff[2], boff[4];
#pragma unroll
    for (int mh = 0; mh < 2; ++mh) {
        const unsigned Lb = (unsigned)(wm + mh * 16 + lm) * 64 + lg * 16;
        aoff[mh] = (int)(Lb ^ (((Lb >> 7) & 7u) << 4)) >> 1;
    }
#pragma unroll
    for (int n = 0; n < 4; ++n) {
        const unsigned Lb = (unsigned)(wn + n * 16 + lm) * 64 + lg * 16;
        boff[n] = (int)(8192u + (Lb ^ (((Lb >> 7) & 7u) << 4))) >> 1;
    }

    f32x4 acc[2][4];
#pragma unroll
    for (int m = 0; m < 2; ++m)
#pragma unroll
        for (int n = 0; n < 4; ++n) acc[m][n] = f32x4{0.f, 0.f, 0.f, 0.f};

#define ISSUE_SUB(u)                                                          \
    do {                                                                      \
        __bf16* sbp = lds + (((u) & 3) << 13);                                \
        const int go = (u) << 5;                                              \
        _Pragma("unroll")                                                     \
        for (int j = 0; j < 2; ++j) gload_lds16(gsrc[j] + go, sbp + ldst[j]); \
    } while (0)

#define PHASE8(SBASE)                                                         \
    do {                                                                      \
        bf16x8 a0 = *(const bf16x8*)(lds + (SBASE) + aoff[0]);                \
        bf16x8 a1 = *(const bf16x8*)(lds + (SBASE) + aoff[1]);                \
        bf16x8 bfr[4];                                                        \
        _Pragma("unroll")                                                     \
        for (int n = 0; n < 4; ++n)                                           \
            bfr[n] = *(const bf16x8*)(lds + (SBASE) + boff[n]);               \
        asm volatile("" ::: "memory");                                        \
        __builtin_amdgcn_s_barrier();                                         \
        __builtin_amdgcn_sched_barrier(0);                                    \
        __builtin_amdgcn_s_setprio(1);                                        \
        _Pragma("unroll")                                                     \
        for (int n = 0; n < 4; ++n)                                           \
            acc[0][n] = __builtin_amdgcn_mfma_f32_16x16x32_bf16(              \
                a0, bfr[n], acc[0][n], 0, 0, 0);                              \
        _Pragma("unroll")                                                     \
        for (int n = 0; n < 4; ++n)                                           \
            acc[1][n] = __builtin_amdgcn_mfma_f32_16x16x32_bf16(              \
                a1, bfr[n], acc[1][n], 0, 0, 0);                              \
        __builtin_amdgcn_s_setprio(0);                                        \
        __builtin_amdgcn_sched_barrier(0);                                    \
        __builtin_amdgcn_s_barrier();                                         \
    } while (0)

    ISSUE_SUB(0); ISSUE_SUB(1); ISSUE_SUB(2); ISSUE_SUB(3);
    asm volatile("s_waitcnt vmcnt(4)" ::: "memory");
    __builtin_amdgcn_s_barrier();

    for (int t = 0; t < NT; ++t) {
        const int sa = ((2 * t) & 3) << 13, sb = ((2 * t + 1) & 3) << 13;
        PHASE8(sa);
        if (t < NT - 2) ISSUE_SUB(2 * t + 4);
        PHASE8(sb);
        if (t < NT - 2) {
            ISSUE_SUB(2 * t + 5);
            asm volatile("s_waitcnt vmcnt(4)" ::: "memory");
        } else if (t == NT - 2) {
            asm volatile("s_waitcnt vmcnt(0)" ::: "memory");
        }
        __builtin_amdgcn_s_barrier();
    }
#undef ISSUE_SUB
#undef PHASE8

#pragma unroll
    for (int m = 0; m < 2; ++m) {
        const int row = bm + wm + m * 16 + lg * 4;
#pragma unroll
        for (int n = 0; n < 4; ++n) {
            const int col = bn + wn + n * 16 + lm;
            const float bvv = bias[col];
#pragma unroll
            for (int r = 0; r < 4; ++r) {
                const size_t idx = (size_t)(row + r) * N + col;
                outp[idx] = resid[idx] + acc[m][n][r] + bvv;
            }
        }
    }
}

// ---------------------------------------------------------------------------
// 128x256 GEMM for fused QKV (768 wgs). MERGED PHASES.
// Epilogue: Q scaled by 0.125*log2e; K bf16 (ldc 2048); V transposed AND
// key-axis permuted within 32-token blocks (zero-shuffle PV downstream).
// ---------------------------------------------------------------------------
__global__ __launch_bounds__(512, 2) void gemm_qkv(const __bf16* __restrict__ A,
                                                   const __bf16* __restrict__ BT,
                                                   const float* __restrict__ bias,
                                                   __bf16* __restrict__ outp,
                                                   __bf16* __restrict__ vTout,
                                                   int M, int N, int K, int NMB) {
    __shared__ __align__(16) __bf16 lds[49152];
    const int bid = blockIdx.x;
    const int c8 = bid & 7, loc = bid >> 3;
    const int MH = NMB >> 3;
    const int bm = (c8 * MH + loc % MH) * 128;
    const int bn = (loc / MH) * 256;
    const int tid = threadIdx.x, l = tid & 63, w = tid >> 6;
    const int wm = (w >> 2) * 64, wn = (w & 3) * 64;
    const int lg = l >> 4, lm = l & 15;
    const int NT = K >> 6;

    const __bf16* gsrc[3];
    int ldst[3];
#pragma unroll
    for (int j = 0; j < 3; ++j) {
        const unsigned X = (unsigned)((j == 0 ? 0 : (j - 1) * 8192) + tid * 16);
        const unsigned L = X ^ (((X >> 7) & 7u) << 4);
        const int row = L >> 6, col = (L & 63) >> 1;
        gsrc[j] = (j == 0 ? A + (size_t)(bm + row) * K : BT + (size_t)(bn + row) * K) + col;
        ldst[j] = ((j == 0 ? 0 : 8192 + (j - 1) * 8192) + (w << 10)) >> 1;
    }
    int aoff[2][2], boff[4];
#pragma unroll
    for (int mh = 0; mh < 2; ++mh)
#pragma unroll
        for (int fr = 0; fr < 2; ++fr) {
            const unsigned Lb = (unsigned)(wm + mh * 32 + fr * 16 + lm) * 64 + lg * 16;
            aoff[mh][fr] = (int)(Lb ^ (((Lb >> 7) & 7u) << 4)) >> 1;
        }
#pragma unroll
    for (int n = 0; n < 4; ++n) {
        const unsigned Lb = (unsigned)(wn + n * 16 + lm) * 64 + lg * 16;
        boff[n] = (int)(8192u + (Lb ^ (((Lb >> 7) & 7u) << 4))) >> 1;
    }

    f32x4 acc[4][4];
#pragma unroll
    for (int m = 0; m < 4; ++m)
#pragma unroll
        for (int n = 0; n < 4; ++n) acc[m][n] = f32x4{0.f, 0.f, 0.f, 0.f};

#define ISSUE_SUB(u)                                                          \
    do {                                                                      \
        __bf16* sbp = lds + ((u) & 3) * 12288;                                \
        const int go = (u) << 5;                                              \
        _Pragma("unroll")                                                     \
        for (int j = 0; j < 3; ++j) gload_lds16(gsrc[j] + go, sbp + ldst[j]); \
    } while (0)

#define PHASE16(SBASE)                                                        \
    do {                                                                      \
        bf16x8 afr[2][2], bfr[4];                                             \
        _Pragma("unroll")                                                     \
        for (int mh = 0; mh < 2; ++mh)                                        \
            _Pragma("unroll")                                                 \
            for (int fr = 0; fr < 2; ++fr)                                    \
                afr[mh][fr] = *(const bf16x8*)(lds + (SBASE) + aoff[mh][fr]); \
        _Pragma("unroll")                                                     \
        for (int n = 0; n < 4; ++n)                                           \
            bfr[n] = *(const bf16x8*)(lds + (SBASE) + boff[n]);               \
        asm volatile("" ::: "memory");                                        \
        __builtin_amdgcn_s_barrier();                                         \
        __builtin_amdgcn_sched_barrier(0);                                    \
        __builtin_amdgcn_s_setprio(1);                                        \
        _Pragma("unroll")                                                     \
        for (int mh = 0; mh < 2; ++mh)                                        \
            _Pragma("unroll")                                                 \
            for (int fr = 0; fr < 2; ++fr)                                    \
                _Pragma("unroll")                                             \
                for (int n = 0; n < 4; ++n)                                   \
                    acc[mh * 2 + fr][n] =                                     \
                        __builtin_amdgcn_mfma_f32_16x16x32_bf16(              \
                            afr[mh][fr], bfr[n], acc[mh * 2 + fr][n], 0, 0, 0);\
        __builtin_amdgcn_s_setprio(0);                                        \
        __builtin_amdgcn_sched_barrier(0);                                    \
        __builtin_amdgcn_s_barrier();                                         \
    } while (0)

    ISSUE_SUB(0); ISSUE_SUB(1); ISSUE_SUB(2); ISSUE_SUB(3);
    asm volatile("s_waitcnt vmcnt(6)" ::: "memory");
    __builtin_amdgcn_s_barrier();

    for (int t = 0; t < NT; ++t) {
        const int sa = ((2 * t) & 3) * 12288, sb = ((2 * t + 1) & 3) * 12288;
        PHASE16(sa);
        if (t < NT - 2) ISSUE_SUB(2 * t + 4);
        PHASE16(sb);
        if (t < NT - 2) {
            ISSUE_SUB(2 * t + 5);
            asm volatile("s_waitcnt vmcnt(6)" ::: "memory");
        } else if (t == NT - 2) {
            asm volatile("s_waitcnt vmcnt(0)" ::: "memory");
        }
        __builtin_amdgcn_s_barrier();
    }
#undef ISSUE_SUB
#undef PHASE16

    const bool isQ = bn < 1024;
#pragma unroll
    for (int m = 0; m < 4; ++m) {
        const int row = bm + wm + m * 16 + lg * 4;
#pragma unroll
        for (int n = 0; n < 4; ++n) {
            const int col = bn + wn + n * 16 + lm;
            const float bvv = bias[col];
            if (bn >= 2048) {
                bf16x4 o;
#pragma unroll
                for (int r = 0; r < 4; ++r) o[r] = (__bf16)(acc[m][n][r] + bvv);
                const int s = row & 1023;   // token within sequence; s%4 == 0
                const int sp = (s & ~31) | (((s >> 2) & 3) << 3) | (((s >> 4) & 1) << 2);
                *(bf16x4*)(vTout + (size_t)((row >> 10) * 1024 + (col - 2048)) * 1024 +
                           sp) = o;
            } else {
#pragma unroll
                for (int r = 0; r < 4; ++r) {
                    float v = acc[m][n][r] + bvv;
                    if (isQ) v *= 0.18033688f;   // 1/8 * log2(e): exp2-domain softmax
                    outp[(size_t)(row + r) * 2048 + col] = (__bf16)v;
                }
            }
        }
    }
}

// ---------------------------------------------------------------------------
// Flash attention fwd, swapped-QK^T, ZERO-SHUFFLE PV, in-register P, lane-local
// stats, soft barriers. TWO KV TILES PER BARRIER PAIR: tiles kt,kt+1 in LDS
// bufs 0,1; joint softmax over 128 keys; barriers halved; the two tiles'
// MFMA/softmax chains interleave in-wave.
// ---------------------------------------------------------------------------
__global__ __launch_bounds__(512, 4) void attn_kernel(const __bf16* __restrict__ qk,
                                                      const __bf16* __restrict__ vT,
                                                      const int* __restrict__ mask,
                                                      __bf16* __restrict__ ctx) {
    const int h = blockIdx.x, qt = blockIdx.y, b = blockIdx.z;
    const int tid = threadIdx.x, w = tid >> 6, l = tid & 63;
    const int lg = l >> 4, lm = l & 15;

    __shared__ __align__(16) __bf16 Ks[2][64][76];
    __shared__ __align__(16) __bf16 Vt[2][64][76];

    const int qrow = qt * 128 + w * 16 + lm;
    const __bf16* qp = qk + (size_t)(b * 1024 + qrow) * 2048 + h * 64 + lg * 8;
    bf16x8 aq[2];
    aq[0] = *(const bf16x8*)qp;
    aq[1] = *(const bf16x8*)(qp + 32);

    const int r0 = tid >> 3, cc0 = (tid & 7) * 8;
    const __bf16* kbase = qk + (size_t)(b * 1024 + r0) * 2048 + 1024 + h * 64 + cc0;
    const __bf16* vbase = vT + (size_t)(b * 1024 + h * 64 + r0) * 1024 + cc0;
    uint4 kregA, vregA, kregB, vregB;
#define ALOAD2(kt)                                                        \
    do {                                                                  \
        kregA = *(const uint4*)(kbase + (size_t)(kt) * 131072);           \
        vregA = *(const uint4*)(vbase + (kt) * 64);                       \
        kregB = *(const uint4*)(kbase + (size_t)((kt) + 1) * 131072);     \
        vregB = *(const uint4*)(vbase + ((kt) + 1) * 64);                 \
    } while (0)
#define AWRITE2()                                                         \
    do {                                                                  \
        *(uint4*)&Ks[0][r0][cc0] = kregA;                                 \
        *(uint4*)&Vt[0][r0][cc0] = vregA;                                 \
        *(uint4*)&Ks[1][r0][cc0] = kregB;                                 \
        *(uint4*)&Vt[1][r0][cc0] = vregB;                                 \
    } while (0)

    ALOAD2(0); AWRITE2(); ALOAD2(2);
    SOFT_BARRIER();

    const int* mbase = mask + b * 1024;
    float mrun = -1e30f, lsum = 0.f;   // stats for query lm (lane-local)
    f32x4 oacc[4];
#pragma unroll
    for (int n = 0; n < 4; ++n) oacc[n] = f32x4{0.f, 0.f, 0.f, 0.f};

    for (int kt = 0; kt < 16; kt += 2) {
        // --- QK^T for both tiles (independent chains) ---
        f32x4 s0[4], s1[4];
        int4 mk0[4], mk1[4];
#pragma unroll
        for (int n = 0; n < 4; ++n) {
            mk0[n] = *(const int4*)(mbase + kt * 64 + n * 16 + lg * 4);
            s0[n] = f32x4{0.f, 0.f, 0.f, 0.f};
#pragma unroll
            for (int kk = 0; kk < 2; ++kk) {
                bf16x8 bk = *(const bf16x8*)&Ks[0][n * 16 + lm][lg * 8 + kk * 32];
                s0[n] = __builtin_amdgcn_mfma_f32_16x16x32_bf16(bk, aq[kk], s0[n], 0, 0, 0);
            }
        }
#pragma unroll
        for (int n = 0; n < 4; ++n) {
            mk1[n] = *(const int4*)(mbase + (kt + 1) * 64 + n * 16 + lg * 4);
            s1[n] = f32x4{0.f, 0.f, 0.f, 0.f};
#pragma unroll
            for (int kk = 0; kk < 2; ++kk) {
                bf16x8 bk = *(const bf16x8*)&Ks[1][n * 16 + lm][lg * 8 + kk * 32];
                s1[n] = __builtin_amdgcn_mfma_f32_16x16x32_bf16(bk, aq[kk], s1[n], 0, 0, 0);
            }
        }
        // --- joint masked max over 128 keys ---
        float p0[4][4], p1[4][4], mloc = -3e38f;
#pragma unroll
        for (int n = 0; n < 4; ++n) {
            p0[n][0] = mk0[n].x ? s0[n][0] : -1e9f;
            p0[n][1] = mk0[n].y ? s0[n][1] : -1e9f;
            p0[n][2] = mk0[n].z ? s0[n][2] : -1e9f;
            p0[n][3] = mk0[n].w ? s0[n][3] : -1e9f;
            mloc = fmaxf(mloc, fmaxf(fmaxf(p0[n][0], p0[n][1]), fmaxf(p0[n][2], p0[n][3])));
        }
#pragma unroll
        for (int n = 0; n < 4; ++n) {
            p1[n][0] = mk1[n].x ? s1[n][0] : -1e9f;
            p1[n][1] = mk1[n].y ? s1[n][1] : -1e9f;
            p1[n][2] = mk1[n].z ? s1[n][2] : -1e9f;
            p1[n][3] = mk1[n].w ? s1[n][3] : -1e9f;
            mloc = fmaxf(mloc, fmaxf(fmaxf(p1[n][0], p1[n][1]), fmaxf(p1[n][2], p1[n][3])));
        }
        mloc = fmaxf(mloc, __shfl_xor(mloc, 16));
        mloc = fmaxf(mloc, __shfl_xor(mloc, 32));
        const float pm = fmaxf(mrun, mloc);
        if (!__all(pm - mrun <= 11.5f)) {        // defer-max (T13), log2 domain
            const float sc = exp2f(mrun - pm);
            mrun = pm;
            lsum *= sc;
#pragma unroll
            for (int n = 0; n < 4; ++n)
#pragma unroll
                for (int r = 0; r < 4; ++r) oacc[n][r] *= sc;
        }
        // --- exp2 + row-sum over both tiles, single cross-lane reduce ---
        float rs = 0.f;
#pragma unroll
        for (int n = 0; n < 4; ++n) {
#pragma unroll
            for (int r = 0; r < 4; ++r) {
                p0[n][r] = exp2f(p0[n][r] - mrun);
                p1[n][r] = exp2f(p1[n][r] - mrun);
            }
            rs += (p0[n][0] + p0[n][1]) + (p0[n][2] + p0[n][3]);
            rs += (p1[n][0] + p1[n][1]) + (p1[n][2] + p1[n][3]);
        }
        rs += __shfl_xor(rs, 16);
        rs += __shfl_xor(rs, 32);
        lsum += rs;
        // --- PV for both tiles (V key-permuted upstream: direct reg pack) ---
#pragma unroll
        for (int kk = 0; kk < 2; ++kk) {
            bf16x8 pfrag;
#pragma unroll
            for (int r = 0; r < 4; ++r) {
                pfrag[r]     = (__bf16)p0[2 * kk][r];
                pfrag[4 + r] = (__bf16)p0[2 * kk + 1][r];
            }
#pragma unroll
            for (int nd = 0; nd < 4; ++nd) {
                bf16x8 vf = *(const bf16x8*)&Vt[0][nd * 16 + lm][lg * 8 + kk * 32];
                oacc[nd] = __builtin_amdgcn_mfma_f32_16x16x32_bf16(vf, pfrag, oacc[nd], 0, 0, 0);
            }
        }
#pragma unroll
        for (int kk = 0; kk < 2; ++kk) {
            bf16x8 pfrag;
#pragma unroll
            for (int r = 0; r < 4; ++r) {
                pfrag[r]     = (__bf16)p1[2 * kk][r];
                pfrag[4 + r] = (__bf16)p1[2 * kk + 1][r];
            }
#pragma unroll
            for (int nd = 0; nd < 4; ++nd) {
                bf16x8 vf = *(const bf16x8*)&Vt[1][nd * 16 + lm][lg * 8 + kk * 32];
                oacc[nd] = __builtin_amdgcn_mfma_f32_16x16x32_bf16(vf, pfrag, oacc[nd], 0, 0, 0);
            }
        }
        SOFT_BARRIER();                  // all reads of bufs 0,1 complete
        if (kt < 14) AWRITE2();          // tiles kt+2,kt+3 (regs from last iter)
        if (kt < 12) ALOAD2(kt + 4);     // prefetch next pair
        SOFT_BARRIER();                  // writes visible for next iteration
    }
#undef ALOAD2
#undef AWRITE2
    const float rinv = 1.0f / lsum;
#pragma unroll
    for (int nd = 0; nd < 4; ++nd) {
        bf16x4 o;
#pragma unroll
        for (int r = 0; r < 4; ++r) o[r] = (__bf16)(oacc[nd][r] * rinv);
        *(bf16x4*)(ctx + (size_t)(b * 1024 + qrow) * 1024 + h * 64 + nd * 16 + lg * 4) = o;
    }
}

// ---------------------------------------------------------------------------
extern "C" void kernel_launch(void* const* d_in, const int* in_sizes, int n_in,
                              void* d_out, int out_size, void* d_ws, size_t ws_size,
                              hipStream_t stream) {
    const float* x    = (const float*)d_in[0];
    const int*   mask = (const int*)d_in[1];
    const float* wq   = (const float*)d_in[2];
    const float* bq   = (const float*)d_in[3];
    const float* wk   = (const float*)d_in[4];
    const float* bk   = (const float*)d_in[5];
    const float* wv   = (const float*)d_in[6];
    const float* bv   = (const float*)d_in[7];
    const float* wo   = (const float*)d_in[8];
    const float* bo   = (const float*)d_in[9];
    const float* w1   = (const float*)d_in[10];
    const float* b1   = (const float*)d_in[11];
    const float* w2   = (const float*)d_in[12];
    const float* b2   = (const float*)d_in[13];
    const float* ln1g = (const float*)d_in[14];
    const float* ln1b = (const float*)d_in[15];
    const float* ln2g = (const float*)d_in[16];
    const float* ln2b = (const float*)d_in[17];
    float* out = (float*)d_out;
    char* ws = (char*)d_ws;

    __bf16* wqkvT = (__bf16*)(ws + 0);          // [3072][1024]  6 MB
    __bf16* woT   = (__bf16*)(ws + 6291456);    // [1024][1024]  2 MB
    __bf16* w1T   = (__bf16*)(ws + 8388608);    // [4096][1024]  8 MB
    __bf16* w2T   = (__bf16*)(ws + 16777216);   // [1024][4096]  8 MB
    float*  bqkv  = (float*)(ws + 25165824);    // [3072]
    __bf16* hb    = (__bf16*)(ws + 25178112);   // [8192][1024] 16 MB
    __bf16* qkb   = (__bf16*)(ws + 41955328);   // [8192][2048] 32 MB
    __bf16* vTb   = (__bf16*)(ws + 75509760);   // [8*16*64][1024] 16 MB
    __bf16* ctxb  = (__bf16*)(ws + 92286976);   // [8192][1024] 16 MB -> 109064192
    __bf16* ff1b  = qkb;                        // [8192][4096] 64 MB overlays

    // weights transpose + bias concat (single launch)
    transpose_all<<<12292, 256, 0, stream>>>(wq, wk, wv, wo, w1, w2,
                                             wqkvT, woT, w1T, w2T,
                                             bq, bk, bv, bqkv);

    // LN1 -> hb
    ln_to_bf16<<<8192, 256, 0, stream>>>(x, ln1g, ln1b, hb);
    // fused QKV (128x256): Q(prescaled)|K -> qkb, V -> vTb^T (key-permuted)
    gemm_qkv<<<768, 512, 0, stream>>>(hb, wqkvT, bqkv, qkb, vTb, 8192, 3072, 1024, 64);
    // attention (head-major grid for XCD-aligned KV reuse)
    attn_kernel<<<dim3(16, 8, 8), 512, 0, stream>>>(qkb, vTb, mask, ctxb);
    // output proj + residual -> d_out (fp32): 128x128 merged-phase, 512 wgs
    gemm128x128<<<512, 512, 0, stream>>>(ctxb, woT, bo, x, out, 8192, 1024, 1024, 64);
    // LN2 -> hb
    ln_to_bf16<<<8192, 256, 0, stream>>>(out, ln2g, ln2b, hb);
    // FFN1 (256^2, relu)
    gemm256<1><<<512, 512, 0, stream>>>(hb, w1T, b1, ff1b, 8192, 4096, 1024, 32);
    // FFN2 + residual: 128x128 merged-phase, 512 wgs
    gemm128x128<<<512, 512, 0, stream>>>(ff1b, w2T, b2, out, out, 8192, 1024, 4096, 64);
}

// Round 14
// 363.411 us; speedup vs baseline: 1.0353x; 1.0353x over previous
//
#include <hip/hip_runtime.h>
#include <hip/hip_bf16.h>

typedef __attribute__((ext_vector_type(8))) __bf16 bf16x8;
typedef __attribute__((ext_vector_type(4))) __bf16 bf16x4;
typedef __attribute__((ext_vector_type(4))) float  f32x4;

__device__ __forceinline__ void gload_lds16(const __bf16* g, __bf16* l) {
    __builtin_amdgcn_global_load_lds(
        (const __attribute__((address_space(1))) void*)g,
        (__attribute__((address_space(3))) void*)l, 16, 0, 0);
}

// Soft barrier: ds-write visibility (lgkmcnt(0)) + rendezvous, but does NOT
// drain vmcnt -> register prefetch loads stay in flight across the barrier.
#define SOFT_BARRIER()                                            \
    do {                                                          \
        asm volatile("s_waitcnt lgkmcnt(0)" ::: "memory");        \
        __builtin_amdgcn_s_barrier();                             \
        asm volatile("" ::: "memory");                            \
    } while (0)

// ---------------------------------------------------------------------------
// All weight transposes (fp32 [K][N] -> bf16 [N][K]) + bias concat, ONE launch.
// ---------------------------------------------------------------------------
__global__ __launch_bounds__(256) void transpose_all(
    const float* __restrict__ wq, const float* __restrict__ wk,
    const float* __restrict__ wv, const float* __restrict__ wo,
    const float* __restrict__ w1, const float* __restrict__ w2,
    __bf16* __restrict__ wqkvT, __bf16* __restrict__ woT,
    __bf16* __restrict__ w1T, __bf16* __restrict__ w2T,
    const float* __restrict__ bq, const float* __restrict__ bk,
    const float* __restrict__ bv, float* __restrict__ bqkv) {
    __shared__ float t[32][33];
    const int bid = blockIdx.x;
    if (bid >= 12288) {   // bias concat tail
        const int i = (bid - 12288) * 256 + threadIdx.x;
        bqkv[i] = bq[i]; bqkv[1024 + i] = bk[i]; bqkv[2048 + i] = bv[i];
        return;
    }
    const float* in; __bf16* out; int K, N, nb, kb;
    if (bid < 4096) {
        const int which = bid >> 10, tt = bid & 1023;
        K = 1024; N = 1024;
        in  = which == 0 ? wq : which == 1 ? wk : which == 2 ? wv : wo;
        out = which == 3 ? woT : wqkvT + (size_t)which * 1048576;
        nb = (tt & 31) * 32; kb = (tt >> 5) * 32;
    } else if (bid < 8192) {
        const int tt = bid - 4096;
        in = w1; out = w1T; K = 1024; N = 4096;
        nb = (tt & 127) * 32; kb = (tt >> 7) * 32;
    } else {
        const int tt = bid - 8192;
        in = w2; out = w2T; K = 4096; N = 1024;
        nb = (tt & 31) * 32; kb = (tt >> 5) * 32;
    }
    const int tx = threadIdx.x & 31, ty = threadIdx.x >> 5;
#pragma unroll
    for (int i = 0; i < 32; i += 8)
        t[ty + i][tx] = in[(size_t)(kb + ty + i) * N + nb + tx];
    __syncthreads();
#pragma unroll
    for (int i = 0; i < 32; i += 8)
        out[(size_t)(nb + ty + i) * K + kb + tx] = (__bf16)t[tx][ty + i];
}

// ---------------------------------------------------------------------------
// LayerNorm over D=1024, one block per row, fp32 in -> bf16 out
// ---------------------------------------------------------------------------
__global__ __launch_bounds__(256) void ln_to_bf16(const float* __restrict__ x,
                                                  const float* __restrict__ g,
                                                  const float* __restrict__ bb,
                                                  __bf16* __restrict__ out) {
    const int row = blockIdx.x, t = threadIdx.x;
    const float4 v = ((const float4*)(x + (size_t)row * 1024))[t];
    float s  = v.x + v.y + v.z + v.w;
    float ss = v.x * v.x + v.y * v.y + v.z * v.z + v.w * v.w;
#pragma unroll
    for (int off = 32; off; off >>= 1) {
        s  += __shfl_down(s, off);
        ss += __shfl_down(ss, off);
    }
    __shared__ float ps[4], pss[4];
    if ((t & 63) == 0) { ps[t >> 6] = s; pss[t >> 6] = ss; }
    __syncthreads();
    s  = ps[0] + ps[1] + ps[2] + ps[3];
    ss = pss[0] + pss[1] + pss[2] + pss[3];
    const float mu   = s * (1.0f / 1024.0f);
    const float var  = ss * (1.0f / 1024.0f) - mu * mu;
    const float rinv = rsqrtf(var + 1e-5f);
    const float4 gv = ((const float4*)g)[t];
    const float4 bv = ((const float4*)bb)[t];
    bf16x4 o;
    o[0] = (__bf16)((v.x - mu) * rinv * gv.x + bv.x);
    o[1] = (__bf16)((v.y - mu) * rinv * gv.y + bv.y);
    o[2] = (__bf16)((v.z - mu) * rinv * gv.z + bv.z);
    o[3] = (__bf16)((v.w - mu) * rinv * gv.w + bv.w);
    *(bf16x4*)(out + (size_t)row * 1024 + 4 * t) = o;
}

// ---------------------------------------------------------------------------
// 256x256 8-phase GEMM (FFN1). 2D per-XCD chunk. MODE 1: relu bf16 out.
// ---------------------------------------------------------------------------
template <int MODE>
__global__ __launch_bounds__(512, 2) void gemm256(const __bf16* __restrict__ A,
                                                  const __bf16* __restrict__ BT,
                                                  const float* __restrict__ bias,
                                                  __bf16* __restrict__ outp,
                                                  int M, int N, int K, int NMB) {
    __shared__ __align__(16) __bf16 lds[65536];
    const int bid = blockIdx.x;
    const int c8 = bid & 7, loc = bid >> 3;       // XCD id, chunk-local index
    const int MH = NMB >> 3;                      // bm rows per XCD chunk
    const int bm = (c8 * MH + loc % MH) * 256;
    const int bn = (loc / MH) * 256;
    const int tid = threadIdx.x, l = tid & 63, w = tid >> 6;
    const int wm = (w >> 2) * 128, wn = (w & 3) * 64;
    const int lg = l >> 4, lm = l & 15;
    const int NT = K >> 6;

    const __bf16* gsrc[4];
    int ldst[4];
#pragma unroll
    for (int j = 0; j < 4; ++j) {
        const unsigned X = (unsigned)(((j & 1) << 13) + (w << 10) + l * 16);
        const unsigned L = X ^ (((X >> 7) & 7u) << 4);
        const int row = L >> 6, col = (L & 63) >> 1;
        gsrc[j] = (j < 2 ? A + (size_t)(bm + row) * K : BT + (size_t)(bn + row) * K) + col;
        ldst[j] = ((j < 2 ? 0 : 16384) + ((j & 1) << 13) + (w << 10)) >> 1;
    }
    int aoff[2][4], boff[4];
#pragma unroll
    for (int mh = 0; mh < 2; ++mh)
#pragma unroll
        for (int fr = 0; fr < 4; ++fr) {
            const unsigned Lb = (unsigned)(wm + mh * 64 + fr * 16 + lm) * 64 + lg * 16;
            aoff[mh][fr] = (int)(Lb ^ (((Lb >> 7) & 7u) << 4)) >> 1;
        }
#pragma unroll
    for (int n = 0; n < 4; ++n) {
        const unsigned Lb = (unsigned)(wn + n * 16 + lm) * 64 + lg * 16;
        boff[n] = (int)(16384u + (Lb ^ (((Lb >> 7) & 7u) << 4))) >> 1;
    }

    f32x4 acc[8][4];
#pragma unroll
    for (int m = 0; m < 8; ++m)
#pragma unroll
        for (int n = 0; n < 4; ++n) acc[m][n] = f32x4{0.f, 0.f, 0.f, 0.f};

#define ISSUE_SUB(u)                                                          \
    do {                                                                      \
        __bf16* sbp = lds + (((u) & 3) << 14);                                \
        const int go = (u) << 5;                                              \
        _Pragma("unroll")                                                     \
        for (int j = 0; j < 4; ++j) gload_lds16(gsrc[j] + go, sbp + ldst[j]); \
    } while (0)

#define MFMA16(MH_, BREG)                                                     \
    do {                                                                      \
        __builtin_amdgcn_s_setprio(1);                                        \
        _Pragma("unroll")                                                     \
        for (int i = 0; i < 4; ++i)                                           \
            _Pragma("unroll")                                                 \
            for (int n = 0; n < 4; ++n)                                       \
                acc[(MH_)*4 + i][n] = __builtin_amdgcn_mfma_f32_16x16x32_bf16(\
                    af[i], BREG[n], acc[(MH_)*4 + i][n], 0, 0, 0);            \
        __builtin_amdgcn_s_setprio(0);                                        \
    } while (0)

    ISSUE_SUB(0); ISSUE_SUB(1); ISSUE_SUB(2); ISSUE_SUB(3);
    asm volatile("s_waitcnt vmcnt(8)" ::: "memory");
    __builtin_amdgcn_s_barrier();

    for (int t = 0; t < NT; ++t) {
        const int sa = ((2 * t) & 3) << 14, sb = ((2 * t + 1) & 3) << 14;
        bf16x8 af[4], b0[4], b1[4];
#pragma unroll
        for (int fr = 0; fr < 4; ++fr) af[fr] = *(const bf16x8*)(lds + sa + aoff[0][fr]);
#pragma unroll
        for (int n = 0; n < 4; ++n) b0[n] = *(const bf16x8*)(lds + sa + boff[n]);
        asm volatile("" ::: "memory");
        __builtin_amdgcn_s_barrier();
        __builtin_amdgcn_sched_barrier(0);
        MFMA16(0, b0);
        __builtin_amdgcn_sched_barrier(0);
        __builtin_amdgcn_s_barrier();
#pragma unroll
        for (int fr = 0; fr < 4; ++fr) af[fr] = *(const bf16x8*)(lds + sa + aoff[1][fr]);
        asm volatile("" ::: "memory");
        __builtin_amdgcn_s_barrier();
        __builtin_amdgcn_sched_barrier(0);
        MFMA16(1, b0);
        __builtin_amdgcn_sched_barrier(0);
        __builtin_amdgcn_s_barrier();
        if (t < NT - 2) ISSUE_SUB(2 * t + 4);
#pragma unroll
        for (int fr = 0; fr < 4; ++fr) af[fr] = *(const bf16x8*)(lds + sb + aoff[0][fr]);
#pragma unroll
        for (int n = 0; n < 4; ++n) b1[n] = *(const bf16x8*)(lds + sb + boff[n]);
        asm volatile("" ::: "memory");
        __builtin_amdgcn_s_barrier();
        __builtin_amdgcn_sched_barrier(0);
        MFMA16(0, b1);
        __builtin_amdgcn_sched_barrier(0);
        __builtin_amdgcn_s_barrier();
#pragma unroll
        for (int fr = 0; fr < 4; ++fr) af[fr] = *(const bf16x8*)(lds + sb + aoff[1][fr]);
        asm volatile("" ::: "memory");
        __builtin_amdgcn_s_barrier();
        __builtin_amdgcn_sched_barrier(0);
        MFMA16(1, b1);
        __builtin_amdgcn_sched_barrier(0);
        __builtin_amdgcn_s_barrier();
        if (t < NT - 2) {
            ISSUE_SUB(2 * t + 5);
            asm volatile("s_waitcnt vmcnt(8)" ::: "memory");
        } else if (t == NT - 2) {
            asm volatile("s_waitcnt vmcnt(0)" ::: "memory");
        }
        __builtin_amdgcn_s_barrier();
    }
#undef ISSUE_SUB
#undef MFMA16

#pragma unroll
    for (int m = 0; m < 8; ++m) {
        const int row = bm + wm + (m >> 2) * 64 + (m & 3) * 16 + lg * 4;
#pragma unroll
        for (int n = 0; n < 4; ++n) {
            const int col = bn + wn + n * 16 + lm;
            const float bvv = bias[col];
#pragma unroll
            for (int r = 0; r < 4; ++r) {
                const float v = acc[m][n][r] + bvv;
                outp[(size_t)(row + r) * N + col] =
                    (MODE == 1) ? (__bf16)fmaxf(v, 0.f) : (__bf16)v;
            }
        }
    }
}

// ---------------------------------------------------------------------------
// 256x128 8-phase GEMM, f32 out + residual (proj / FFN2, N=1024). PROVEN (r9).
// ---------------------------------------------------------------------------
__global__ __launch_bounds__(512, 2) void gemm256x128(const __bf16* __restrict__ A,
                                                      const __bf16* __restrict__ BT,
                                                      const float* __restrict__ bias,
                                                      const float* __restrict__ resid,
                                                      float* __restrict__ outp,
                                                      int M, int N, int K, int NMB) {
    __shared__ __align__(16) __bf16 lds[49152];
    const int bid = blockIdx.x;
    const int c8 = bid & 7, loc = bid >> 3;
    const int MH = NMB >> 3;
    const int bm = (c8 * MH + loc % MH) * 256;
    const int bn = (loc / MH) * 128;
    const int tid = threadIdx.x, l = tid & 63, w = tid >> 6;
    const int wm = (w >> 1) * 64, wn = (w & 1) * 64;
    const int lg = l >> 4, lm = l & 15;
    const int NT = K >> 6;

    const __bf16* gsrc[3];
    int ldst[3];
#pragma unroll
    for (int j = 0; j < 3; ++j) {
        const unsigned X = (unsigned)((j == 1 ? 8192 : 0) + tid * 16);
        const unsigned L = X ^ (((X >> 7) & 7u) << 4);
        const int row = L >> 6, col = (L & 63) >> 1;
        gsrc[j] = (j < 2 ? A + (size_t)(bm + row) * K : BT + (size_t)(bn + row) * K) + col;
        ldst[j] = ((j < 2 ? (j << 13) : 16384) + (w << 10)) >> 1;
    }
    int aoff[2][2], boff[4];
#pragma unroll
    for (int mh = 0; mh < 2; ++mh)
#pragma unroll
        for (int fr = 0; fr < 2; ++fr) {
            const unsigned Lb = (unsigned)(wm + mh * 32 + fr * 16 + lm) * 64 + lg * 16;
            aoff[mh][fr] = (int)(Lb ^ (((Lb >> 7) & 7u) << 4)) >> 1;
        }
#pragma unroll
    for (int n = 0; n < 4; ++n) {
        const unsigned Lb = (unsigned)(wn + n * 16 + lm) * 64 + lg * 16;
        boff[n] = (int)(16384u + (Lb ^ (((Lb >> 7) & 7u) << 4))) >> 1;
    }

    f32x4 acc[4][4];
#pragma unroll
    for (int m = 0; m < 4; ++m)
#pragma unroll
        for (int n = 0; n < 4; ++n) acc[m][n] = f32x4{0.f, 0.f, 0.f, 0.f};

#define ISSUE_SUB(u)                                                          \
    do {                                                                      \
        __bf16* sbp = lds + ((u) & 3) * 12288;                                \
        const int go = (u) << 5;                                              \
        _Pragma("unroll")                                                     \
        for (int j = 0; j < 3; ++j) gload_lds16(gsrc[j] + go, sbp + ldst[j]); \
    } while (0)

#define MFMA8(MH_, BREG)                                                      \
    do {                                                                      \
        __builtin_amdgcn_s_setprio(1);                                        \
        _Pragma("unroll")                                                     \
        for (int i = 0; i < 2; ++i)                                           \
            _Pragma("unroll")                                                 \
            for (int n = 0; n < 4; ++n)                                       \
                acc[(MH_)*2 + i][n] = __builtin_amdgcn_mfma_f32_16x16x32_bf16(\
                    af[i], BREG[n], acc[(MH_)*2 + i][n], 0, 0, 0);            \
        __builtin_amdgcn_s_setprio(0);                                        \
    } while (0)

    ISSUE_SUB(0); ISSUE_SUB(1); ISSUE_SUB(2); ISSUE_SUB(3);
    asm volatile("s_waitcnt vmcnt(6)" ::: "memory");
    __builtin_amdgcn_s_barrier();

    for (int t = 0; t < NT; ++t) {
        const int sa = ((2 * t) & 3) * 12288, sb = ((2 * t + 1) & 3) * 12288;
        bf16x8 af[2], b0[4], b1[4];
#pragma unroll
        for (int fr = 0; fr < 2; ++fr) af[fr] = *(const bf16x8*)(lds + sa + aoff[0][fr]);
#pragma unroll
        for (int n = 0; n < 4; ++n) b0[n] = *(const bf16x8*)(lds + sa + boff[n]);
        asm volatile("" ::: "memory");
        __builtin_amdgcn_s_barrier();
        __builtin_amdgcn_sched_barrier(0);
        MFMA8(0, b0);
        __builtin_amdgcn_sched_barrier(0);
        __builtin_amdgcn_s_barrier();
#pragma unroll
        for (int fr = 0; fr < 2; ++fr) af[fr] = *(const bf16x8*)(lds + sa + aoff[1][fr]);
        asm volatile("" ::: "memory");
        __builtin_amdgcn_s_barrier();
        __builtin_amdgcn_sched_barrier(0);
        MFMA8(1, b0);
        __builtin_amdgcn_sched_barrier(0);
        __builtin_amdgcn_s_barrier();
        if (t < NT - 2) ISSUE_SUB(2 * t + 4);
#pragma unroll
        for (int fr = 0; fr < 2; ++fr) af[fr] = *(const bf16x8*)(lds + sb + aoff[0][fr]);
#pragma unroll
        for (int n = 0; n < 4; ++n) b1[n] = *(const bf16x8*)(lds + sb + boff[n]);
        asm volatile("" ::: "memory");
        __builtin_amdgcn_s_barrier();
        __builtin_amdgcn_sched_barrier(0);
        MFMA8(0, b1);
        __builtin_amdgcn_sched_barrier(0);
        __builtin_amdgcn_s_barrier();
#pragma unroll
        for (int fr = 0; fr < 2; ++fr) af[fr] = *(const bf16x8*)(lds + sb + aoff[1][fr]);
        asm volatile("" ::: "memory");
        __builtin_amdgcn_s_barrier();
        __builtin_amdgcn_sched_barrier(0);
        MFMA8(1, b1);
        __builtin_amdgcn_sched_barrier(0);
        __builtin_amdgcn_s_barrier();
        if (t < NT - 2) {
            ISSUE_SUB(2 * t + 5);
            asm volatile("s_waitcnt vmcnt(6)" ::: "memory");
        } else if (t == NT - 2) {
            asm volatile("s_waitcnt vmcnt(0)" ::: "memory");
        }
        __builtin_amdgcn_s_barrier();
    }
#undef ISSUE_SUB
#undef MFMA8

#pragma unroll
    for (int m = 0; m < 4; ++m) {
        const int row = bm + wm + m * 16 + lg * 4;
#pragma unroll
        for (int n = 0; n < 4; ++n) {
            const int col = bn + wn + n * 16 + lm;
            const float bvv = bias[col];
#pragma unroll
            for (int r = 0; r < 4; ++r) {
                const size_t idx = (size_t)(row + r) * N + col;
                outp[idx] = resid[idx] + acc[m][n][r] + bvv;
            }
        }
    }
}

// ---------------------------------------------------------------------------
// 128x256 GEMM for fused QKV (768 wgs). MERGED PHASES (r12, passed).
// Epilogue: Q scaled by 0.125*log2e; K bf16 (ldc 2048); V transposed AND
// key-axis permuted within 32-token blocks (zero-shuffle PV downstream).
// ---------------------------------------------------------------------------
__global__ __launch_bounds__(512, 2) void gemm_qkv(const __bf16* __restrict__ A,
                                                   const __bf16* __restrict__ BT,
                                                   const float* __restrict__ bias,
                                                   __bf16* __restrict__ outp,
                                                   __bf16* __restrict__ vTout,
                                                   int M, int N, int K, int NMB) {
    __shared__ __align__(16) __bf16 lds[49152];
    const int bid = blockIdx.x;
    const int c8 = bid & 7, loc = bid >> 3;
    const int MH = NMB >> 3;
    const int bm = (c8 * MH + loc % MH) * 128;
    const int bn = (loc / MH) * 256;
    const int tid = threadIdx.x, l = tid & 63, w = tid >> 6;
    const int wm = (w >> 2) * 64, wn = (w & 3) * 64;
    const int lg = l >> 4, lm = l & 15;
    const int NT = K >> 6;

    const __bf16* gsrc[3];
    int ldst[3];
#pragma unroll
    for (int j = 0; j < 3; ++j) {
        const unsigned X = (unsigned)((j == 0 ? 0 : (j - 1) * 8192) + tid * 16);
        const unsigned L = X ^ (((X >> 7) & 7u) << 4);
        const int row = L >> 6, col = (L & 63) >> 1;
        gsrc[j] = (j == 0 ? A + (size_t)(bm + row) * K : BT + (size_t)(bn + row) * K) + col;
        ldst[j] = ((j == 0 ? 0 : 8192 + (j - 1) * 8192) + (w << 10)) >> 1;
    }
    int aoff[2][2], boff[4];
#pragma unroll
    for (int mh = 0; mh < 2; ++mh)
#pragma unroll
        for (int fr = 0; fr < 2; ++fr) {
            const unsigned Lb = (unsigned)(wm + mh * 32 + fr * 16 + lm) * 64 + lg * 16;
            aoff[mh][fr] = (int)(Lb ^ (((Lb >> 7) & 7u) << 4)) >> 1;
        }
#pragma unroll
    for (int n = 0; n < 4; ++n) {
        const unsigned Lb = (unsigned)(wn + n * 16 + lm) * 64 + lg * 16;
        boff[n] = (int)(8192u + (Lb ^ (((Lb >> 7) & 7u) << 4))) >> 1;
    }

    f32x4 acc[4][4];
#pragma unroll
    for (int m = 0; m < 4; ++m)
#pragma unroll
        for (int n = 0; n < 4; ++n) acc[m][n] = f32x4{0.f, 0.f, 0.f, 0.f};

#define ISSUE_SUB(u)                                                          \
    do {                                                                      \
        __bf16* sbp = lds + ((u) & 3) * 12288;                                \
        const int go = (u) << 5;                                              \
        _Pragma("unroll")                                                     \
        for (int j = 0; j < 3; ++j) gload_lds16(gsrc[j] + go, sbp + ldst[j]); \
    } while (0)

#define PHASE16(SBASE)                                                        \
    do {                                                                      \
        bf16x8 afr[2][2], bfr[4];                                             \
        _Pragma("unroll")                                                     \
        for (int mh = 0; mh < 2; ++mh)                                        \
            _Pragma("unroll")                                                 \
            for (int fr = 0; fr < 2; ++fr)                                    \
                afr[mh][fr] = *(const bf16x8*)(lds + (SBASE) + aoff[mh][fr]); \
        _Pragma("unroll")                                                     \
        for (int n = 0; n < 4; ++n)                                           \
            bfr[n] = *(const bf16x8*)(lds + (SBASE) + boff[n]);               \
        asm volatile("" ::: "memory");                                        \
        __builtin_amdgcn_s_barrier();                                         \
        __builtin_amdgcn_sched_barrier(0);                                    \
        __builtin_amdgcn_s_setprio(1);                                        \
        _Pragma("unroll")                                                     \
        for (int mh = 0; mh < 2; ++mh)                                        \
            _Pragma("unroll")                                                 \
            for (int fr = 0; fr < 2; ++fr)                                    \
                _Pragma("unroll")                                             \
                for (int n = 0; n < 4; ++n)                                   \
                    acc[mh * 2 + fr][n] =                                     \
                        __builtin_amdgcn_mfma_f32_16x16x32_bf16(              \
                            afr[mh][fr], bfr[n], acc[mh * 2 + fr][n], 0, 0, 0);\
        __builtin_amdgcn_s_setprio(0);                                        \
        __builtin_amdgcn_sched_barrier(0);                                    \
        __builtin_amdgcn_s_barrier();                                         \
    } while (0)

    ISSUE_SUB(0); ISSUE_SUB(1); ISSUE_SUB(2); ISSUE_SUB(3);
    asm volatile("s_waitcnt vmcnt(6)" ::: "memory");
    __builtin_amdgcn_s_barrier();

    for (int t = 0; t < NT; ++t) {
        const int sa = ((2 * t) & 3) * 12288, sb = ((2 * t + 1) & 3) * 12288;
        PHASE16(sa);
        if (t < NT - 2) ISSUE_SUB(2 * t + 4);
        PHASE16(sb);
        if (t < NT - 2) {
            ISSUE_SUB(2 * t + 5);
            asm volatile("s_waitcnt vmcnt(6)" ::: "memory");
        } else if (t == NT - 2) {
            asm volatile("s_waitcnt vmcnt(0)" ::: "memory");
        }
        __builtin_amdgcn_s_barrier();
    }
#undef ISSUE_SUB
#undef PHASE16

    const bool isQ = bn < 1024;
#pragma unroll
    for (int m = 0; m < 4; ++m) {
        const int row = bm + wm + m * 16 + lg * 4;
#pragma unroll
        for (int n = 0; n < 4; ++n) {
            const int col = bn + wn + n * 16 + lm;
            const float bvv = bias[col];
            if (bn >= 2048) {
                bf16x4 o;
#pragma unroll
                for (int r = 0; r < 4; ++r) o[r] = (__bf16)(acc[m][n][r] + bvv);
                const int s = row & 1023;   // token within sequence; s%4 == 0
                const int sp = (s & ~31) | (((s >> 2) & 3) << 3) | (((s >> 4) & 1) << 2);
                *(bf16x4*)(vTout + (size_t)((row >> 10) * 1024 + (col - 2048)) * 1024 +
                           sp) = o;
            } else {
#pragma unroll
                for (int r = 0; r < 4; ++r) {
                    float v = acc[m][n][r] + bvv;
                    if (isQ) v *= 0.18033688f;   // 1/8 * log2(e): exp2-domain softmax
                    outp[(size_t)(row + r) * 2048 + col] = (__bf16)v;
                }
            }
        }
    }
}

// ---------------------------------------------------------------------------
// Flash attention fwd, swapped-QK^T, ZERO-SHUFFLE PV (V key-permuted upstream),
// in-register P, lane-local online-softmax stats, soft barriers, dual-buffer
// (write next tile into idle buffer while computing current). PROVEN (r9-r12).
// ---------------------------------------------------------------------------
__global__ __launch_bounds__(512, 4) void attn_kernel(const __bf16* __restrict__ qk,
                                                      const __bf16* __restrict__ vT,
                                                      const int* __restrict__ mask,
                                                      __bf16* __restrict__ ctx) {
    const int h = blockIdx.x, qt = blockIdx.y, b = blockIdx.z;
    const int tid = threadIdx.x, w = tid >> 6, l = tid & 63;
    const int lg = l >> 4, lm = l & 15;

    __shared__ __align__(16) __bf16 Ks[2][64][76];
    __shared__ __align__(16) __bf16 Vt[2][64][76];

    const int qrow = qt * 128 + w * 16 + lm;
    const __bf16* qp = qk + (size_t)(b * 1024 + qrow) * 2048 + h * 64 + lg * 8;
    bf16x8 aq[2];
    aq[0] = *(const bf16x8*)qp;
    aq[1] = *(const bf16x8*)(qp + 32);

    const int r0 = tid >> 3, cc0 = (tid & 7) * 8;
    const __bf16* kbase = qk + (size_t)(b * 1024 + r0) * 2048 + 1024 + h * 64 + cc0;
    const __bf16* vbase = vT + (size_t)(b * 1024 + h * 64 + r0) * 1024 + cc0;
    uint4 kreg, vreg;
#define ALOAD(kt)                                                      \
    do {                                                               \
        kreg = *(const uint4*)(kbase + (size_t)(kt) * 131072);         \
        vreg = *(const uint4*)(vbase + (kt) * 64);                     \
    } while (0)
#define AWRITE(bf)                                                     \
    do {                                                               \
        *(uint4*)&Ks[bf][r0][cc0] = kreg;                              \
        *(uint4*)&Vt[bf][r0][cc0] = vreg;                              \
    } while (0)

    ALOAD(0); AWRITE(0); ALOAD(1);
    SOFT_BARRIER();

    const int* mbase = mask + b * 1024;
    float mrun = -1e30f, lsum = 0.f;
    f32x4 oacc[4];
#pragma unroll
    for (int n = 0; n < 4; ++n) oacc[n] = f32x4{0.f, 0.f, 0.f, 0.f};

    for (int kt = 0; kt < 16; ++kt) {
        const int cur = kt & 1;
        if (kt < 15) AWRITE(cur ^ 1);
        if (kt < 14) ALOAD(kt + 2);
        f32x4 sacc[4];
        int4 mk4[4];
#pragma unroll
        for (int n = 0; n < 4; ++n) {
            mk4[n] = *(const int4*)(mbase + kt * 64 + n * 16 + lg * 4);
            sacc[n] = f32x4{0.f, 0.f, 0.f, 0.f};
#pragma unroll
            for (int kk = 0; kk < 2; ++kk) {
                bf16x8 bk = *(const bf16x8*)&Ks[cur][n * 16 + lm][lg * 8 + kk * 32];
                sacc[n] = __builtin_amdgcn_mfma_f32_16x16x32_bf16(bk, aq[kk], sacc[n], 0, 0, 0);
            }
        }
        float p[4][4], mn[4];
#pragma unroll
        for (int n = 0; n < 4; ++n) {
            p[n][0] = mk4[n].x ? sacc[n][0] : -1e9f;
            p[n][1] = mk4[n].y ? sacc[n][1] : -1e9f;
            p[n][2] = mk4[n].z ? sacc[n][2] : -1e9f;
            p[n][3] = mk4[n].w ? sacc[n][3] : -1e9f;
            mn[n] = fmaxf(fmaxf(p[n][0], p[n][1]), fmaxf(p[n][2], p[n][3]));
        }
        float mloc = fmaxf(fmaxf(mn[0], mn[1]), fmaxf(mn[2], mn[3]));
        mloc = fmaxf(mloc, __shfl_xor(mloc, 16));
        mloc = fmaxf(mloc, __shfl_xor(mloc, 32));
        const float pm = fmaxf(mrun, mloc);
        if (!__all(pm - mrun <= 11.5f)) {        // defer-max (T13), log2 domain
            const float sc = exp2f(mrun - pm);
            mrun = pm;
            lsum *= sc;
#pragma unroll
            for (int n = 0; n < 4; ++n)
#pragma unroll
                for (int r = 0; r < 4; ++r) oacc[n][r] *= sc;
        }
        float rsn[4];
#pragma unroll
        for (int n = 0; n < 4; ++n) {
#pragma unroll
            for (int r = 0; r < 4; ++r) p[n][r] = exp2f(p[n][r] - mrun);
            rsn[n] = (p[n][0] + p[n][1]) + (p[n][2] + p[n][3]);
        }
        float rs = (rsn[0] + rsn[1]) + (rsn[2] + rsn[3]);
        rs += __shfl_xor(rs, 16);
        rs += __shfl_xor(rs, 32);
        lsum += rs;
        // PV: O += V^T_frag(A) x P_frag(B). V key-axis pre-permuted so the
        // natural in-lane pack of p[][] IS the B-fragment. No cross-lane ops.
#pragma unroll
        for (int kk = 0; kk < 2; ++kk) {
            bf16x8 pfrag;
#pragma unroll
            for (int r = 0; r < 4; ++r) {
                pfrag[r]     = (__bf16)p[2 * kk][r];
                pfrag[4 + r] = (__bf16)p[2 * kk + 1][r];
            }
#pragma unroll
            for (int nd = 0; nd < 4; ++nd) {
                bf16x8 vf = *(const bf16x8*)&Vt[cur][nd * 16 + lm][lg * 8 + kk * 32];
                oacc[nd] = __builtin_amdgcn_mfma_f32_16x16x32_bf16(vf, pfrag, oacc[nd], 0, 0, 0);
            }
        }
        SOFT_BARRIER();   // read(cur) done wave-wide; write(cur^1) visible
    }
#undef ALOAD
#undef AWRITE
    const float rinv = 1.0f / lsum;
#pragma unroll
    for (int nd = 0; nd < 4; ++nd) {
        bf16x4 o;
#pragma unroll
        for (int r = 0; r < 4; ++r) o[r] = (__bf16)(oacc[nd][r] * rinv);
        *(bf16x4*)(ctx + (size_t)(b * 1024 + qrow) * 1024 + h * 64 + nd * 16 + lg * 4) = o;
    }
}

// ---------------------------------------------------------------------------
extern "C" void kernel_launch(void* const* d_in, const int* in_sizes, int n_in,
                              void* d_out, int out_size, void* d_ws, size_t ws_size,
                              hipStream_t stream) {
    const float* x    = (const float*)d_in[0];
    const int*   mask = (const int*)d_in[1];
    const float* wq   = (const float*)d_in[2];
    const float* bq   = (const float*)d_in[3];
    const float* wk   = (const float*)d_in[4];
    const float* bk   = (const float*)d_in[5];
    const float* wv   = (const float*)d_in[6];
    const float* bv   = (const float*)d_in[7];
    const float* wo   = (const float*)d_in[8];
    const float* bo   = (const float*)d_in[9];
    const float* w1   = (const float*)d_in[10];
    const float* b1   = (const float*)d_in[11];
    const float* w2   = (const float*)d_in[12];
    const float* b2   = (const float*)d_in[13];
    const float* ln1g = (const float*)d_in[14];
    const float* ln1b = (const float*)d_in[15];
    const float* ln2g = (const float*)d_in[16];
    const float* ln2b = (const float*)d_in[17];
    float* out = (float*)d_out;
    char* ws = (char*)d_ws;

    __bf16* wqkvT = (__bf16*)(ws + 0);          // [3072][1024]  6 MB
    __bf16* woT   = (__bf16*)(ws + 6291456);    // [1024][1024]  2 MB
    __bf16* w1T   = (__bf16*)(ws + 8388608);    // [4096][1024]  8 MB
    __bf16* w2T   = (__bf16*)(ws + 16777216);   // [1024][4096]  8 MB
    float*  bqkv  = (float*)(ws + 25165824);    // [3072]
    __bf16* hb    = (__bf16*)(ws + 25178112);   // [8192][1024] 16 MB
    __bf16* qkb   = (__bf16*)(ws + 41955328);   // [8192][2048] 32 MB
    __bf16* vTb   = (__bf16*)(ws + 75509760);   // [8*16*64][1024] 16 MB
    __bf16* ctxb  = (__bf16*)(ws + 92286976);   // [8192][1024] 16 MB -> 109064192
    __bf16* ff1b  = qkb;                        // [8192][4096] 64 MB overlays

    // weights transpose + bias concat (single launch)
    transpose_all<<<12292, 256, 0, stream>>>(wq, wk, wv, wo, w1, w2,
                                             wqkvT, woT, w1T, w2T,
                                             bq, bk, bv, bqkv);

    // LN1 -> hb
    ln_to_bf16<<<8192, 256, 0, stream>>>(x, ln1g, ln1b, hb);
    // fused QKV (128x256): Q(prescaled)|K -> qkb, V -> vTb^T (key-permuted)
    gemm_qkv<<<768, 512, 0, stream>>>(hb, wqkvT, bqkv, qkb, vTb, 8192, 3072, 1024, 64);
    // attention (head-major grid for XCD-aligned KV reuse)
    attn_kernel<<<dim3(16, 8, 8), 512, 0, stream>>>(qkb, vTb, mask, ctxb);
    // output proj + residual -> d_out (fp32)
    gemm256x128<<<256, 512, 0, stream>>>(ctxb, woT, bo, x, out, 8192, 1024, 1024, 32);
    // LN2 -> hb
    ln_to_bf16<<<8192, 256, 0, stream>>>(out, ln2g, ln2b, hb);
    // FFN1 (256^2, relu)
    gemm256<1><<<512, 512, 0, stream>>>(hb, w1T, b1, ff1b, 8192, 4096, 1024, 32);
    // FFN2 + residual
    gemm256x128<<<256, 512, 0, stream>>>(ff1b, w2T, b2, out, out, 8192, 1024, 4096, 32);
}